// Round 8
// baseline (333.675 us; speedup 1.0000x reference)
//
#include <hip/hip_runtime.h>
#include <hip/hip_fp16.h>
#include <math.h>

#define HID 128
#define NCLS 32
#define BCAP 12288   // per-bucket capacity in bins (mean 8704, +38 sigma)
#define SCAP 9728    // LDS sort capacity (mean 8704, +11 sigma)

typedef _Float16 half8 __attribute__((ext_vector_type(8)));
typedef _Float16 h2 __attribute__((ext_vector_type(2)));
typedef float f32x4 __attribute__((ext_vector_type(4)));

__device__ __forceinline__ void gload_lds16(const void* g, void* l) {
  __builtin_amdgcn_global_load_lds(
      (const __attribute__((address_space(1))) void*)g,
      (__attribute__((address_space(3))) void*)l, 16, 0, 0);
}

__device__ __forceinline__ h2 pk_max(h2 a, h2 b) {
  return __builtin_elementwise_max(a, b);   // v_pk_max_f16
}

// ---------------------------------------------------------------- prep
__global__ void k_prep_x(const float* __restrict__ x, __half* __restrict__ xa,
                         int total4) {
  int i = blockIdx.x * blockDim.x + threadIdx.x;
  if (i >= total4) return;
  float4 v = ((const float4*)x)[i];
  __half2* o = (__half2*)xa + i * 2;
  o[0] = __floats2half2_rn(v.x, v.y);
  o[1] = __floats2half2_rn(v.z, v.w);
}

__global__ void k_prep_w(const float* __restrict__ Ws, __half* __restrict__ Wt,
                         int total) {
  int i = blockIdx.x * blockDim.x + threadIdx.x;
  if (i >= total) return;
  int l = i >> 14, r = i & 16383;
  int nn = r >> 7, k = r & 127;
  Wt[i] = __float2half_rn(Ws[(l << 14) + k * HID + nn]);
}

// ---------------------------------------------------------------- binned CSR build
__global__ __launch_bounds__(1024) void k_bin(const int* __restrict__ ei,
                                              const float* __restrict__ norm,
                                              int* __restrict__ bucket_cur,
                                              int2* __restrict__ bins,
                                              int E, int T) {
  __shared__ int bcnt[256];
  __shared__ int bbase[256];
  int tid = threadIdx.x;
  if (tid < 256) bcnt[tid] = 0;
  __syncthreads();
  int base = blockIdx.x * 8192;
  int2 ent[8];
  int bk[8];
  #pragma unroll
  for (int i = 0; i < 8; ++i) {
    int e = base + (i << 10) + tid;
    bk[i] = -1;
    if (e < T) {
      int src, dst;
      if (e < E) { src = ei[e]; dst = ei[E + e]; } else { src = dst = e - E; }
      bk[i] = dst >> 9;
      ent[i] = make_int2(src | ((dst & 511) << 17), __float_as_int(norm[e]));
      atomicAdd(&bcnt[bk[i]], 1);
    }
  }
  __syncthreads();
  if (tid < 256) {
    int c = bcnt[tid];
    bbase[tid] = c ? atomicAdd(&bucket_cur[tid], c) : 0;
    bcnt[tid] = 0;
  }
  __syncthreads();
  #pragma unroll
  for (int i = 0; i < 8; ++i) {
    if (bk[i] >= 0) {
      int pos = bbase[bk[i]] + atomicAdd(&bcnt[bk[i]], 1);
      bins[(size_t)bk[i] * BCAP + pos] = ent[i];
    }
  }
}

__global__ __launch_bounds__(256) void k_bscan(const int* __restrict__ bucket_cur,
                                               int* __restrict__ bucket_off, int nb) {
  __shared__ int a[256];
  int tid = threadIdx.x;
  int orig = (tid < nb) ? bucket_cur[tid] : 0;
  a[tid] = orig;
  __syncthreads();
  for (int d = 1; d < 256; d <<= 1) {
    int t = (tid >= d) ? a[tid - d] : 0;
    __syncthreads();
    a[tid] += t;
    __syncthreads();
  }
  if (tid < nb) bucket_off[tid] = a[tid] - orig;
  if (tid == nb - 1) bucket_off[nb] = a[tid];
}

__global__ __launch_bounds__(1024) void k_sortbucket(
    const int2* __restrict__ bins, const int* __restrict__ bucket_off,
    int2* __restrict__ csr, int* __restrict__ row_off, int n, int nb) {
  __shared__ int2 sorted[SCAP];
  __shared__ int scnt[512];
  __shared__ int wsum[8];
  int b = blockIdx.x, tid = threadIdx.x;
  int goff = bucket_off[b];
  int cnt = bucket_off[b + 1] - goff;
  if (cnt > SCAP) cnt = SCAP;
  const int2* src = bins + (size_t)b * BCAP;
  int2 myent[10];
  #pragma unroll
  for (int i = 0; i < 10; ++i) {
    int j = tid + (i << 10);
    if (j < cnt) myent[i] = src[j];
  }
  if (tid < 512) scnt[tid] = 0;
  __syncthreads();
  #pragma unroll
  for (int i = 0; i < 10; ++i) {
    int j = tid + (i << 10);
    if (j < cnt) atomicAdd(&scnt[((unsigned)myent[i].x) >> 17], 1);
  }
  __syncthreads();
  int lane = tid & 63, wid = tid >> 6;
  int v = (tid < 512) ? scnt[tid] : 0;
  int incl = v;
  #pragma unroll
  for (int d = 1; d < 64; d <<= 1) {
    int t = __shfl_up(incl, d, 64);
    if (lane >= d) incl += t;
  }
  if (tid < 512 && lane == 63) wsum[wid] = incl;
  __syncthreads();
  if (tid == 0) {
    int s = 0;
    #pragma unroll
    for (int i = 0; i < 8; ++i) { int t = wsum[i]; wsum[i] = s; s += t; }
  }
  __syncthreads();
  int excl = incl - v + ((tid < 512) ? wsum[wid] : 0);
  int node = (b << 9) + tid;
  if (tid < 512 && node < n) row_off[node] = goff + excl;
  if (b == nb - 1 && tid == 0) row_off[n] = bucket_off[nb];
  __syncthreads();
  if (tid < 512) scnt[tid] = excl;
  __syncthreads();
  #pragma unroll
  for (int i = 0; i < 10; ++i) {
    int j = tid + (i << 10);
    if (j < cnt) {
      int2 e = myent[i];
      int pos = atomicAdd(&scnt[((unsigned)e.x) >> 17], 1);
      if (pos < SCAP) sorted[pos] = make_int2(e.x & 0x1FFFF, e.y);
    }
  }
  __syncthreads();
  for (int j = tid; j < cnt; j += 1024) csr[goff + j] = sorted[j];
}

// ---------------------------------------------------------------- MFMA GEMM
// 128 rows/block, 256 thr (4 waves x 32 rows), LDS: W 32KB + X 32KB (2 blk/CU).
// 64 MFMA/wave per block (vs 32 at 64-row tiles).
__global__ __launch_bounds__(256) void k_gemm_mfma(const __half* __restrict__ X,
                                                   const __half* __restrict__ Wl,
                                                   __half* __restrict__ H, int n) {
  __shared__ char lds[65536];
  char* ldsW = lds;
  char* ldsX = lds + 32768;
  int tid = threadIdx.x, lane = tid & 63, w = tid >> 6;
  int row0 = blockIdx.x * 128;
  int rows = n - row0; if (rows > 128) rows = 128;
  int vbytes = rows << 8;

  // stage W (32KB): wave w covers [w*8192, +8192)
  #pragma unroll
  for (int it = 0; it < 8; ++it) {
    int d = (w << 13) + (it << 10) + (lane << 4);
    int src = d ^ (((d >> 8) & 7) << 4);
    gload_lds16((const char*)Wl + src, ldsW + (w << 13) + (it << 10));
  }
  // stage X tile (32KB)
  #pragma unroll
  for (int it = 0; it < 8; ++it) {
    int d = (w << 13) + (it << 10) + (lane << 4);
    if (d < vbytes) {
      int src = d ^ (((d >> 8) & 7) << 4);
      gload_lds16((const char*)X + ((size_t)row0 << 8) + src,
                  ldsX + (w << 13) + (it << 10));
    }
  }
  __syncthreads();

  int l15 = lane & 15, lhi = lane >> 4;
  int wr = w << 5;                     // wave's 32-row base
  half8 a[2][4];
  #pragma unroll
  for (int g = 0; g < 2; ++g) {
    int m = wr + (g << 4) + l15;
    #pragma unroll
    for (int s = 0; s < 4; ++s) {
      int d = (m << 8) + (s << 6) + (lhi << 4);
      a[g][s] = *(const half8*)(ldsX + (d ^ ((m & 7) << 4)));
    }
  }
  f32x4 acc[2][8] = {};
  #pragma unroll
  for (int s = 0; s < 4; ++s) {
    #pragma unroll
    for (int t = 0; t < 8; ++t) {
      int nn = (t << 4) + l15;
      int d = (nn << 8) + (s << 6) + (lhi << 4);
      half8 b = *(const half8*)(ldsW + (d ^ ((nn & 7) << 4)));
      acc[0][t] = __builtin_amdgcn_mfma_f32_16x16x32_f16(a[0][s], b, acc[0][t], 0, 0, 0);
      acc[1][t] = __builtin_amdgcn_mfma_f32_16x16x32_f16(a[1][s], b, acc[1][t], 0, 0, 0);
    }
  }
  #pragma unroll
  for (int g = 0; g < 2; ++g) {
    #pragma unroll
    for (int t = 0; t < 8; ++t) {
      int col = (t << 4) + l15;
      #pragma unroll
      for (int r = 0; r < 4; ++r) {
        int row = row0 + wr + (g << 4) + (lhi << 2) + r;
        if (row < n) H[(size_t)row * HID + col] = __float2half_rn(acc[g][t][r]);
      }
    }
  }
}

// ---------------------------------------------------------------- aggregate
// wave per node; quarter-wave per edge (16 lanes x 16B), 4x unroll -> 16 edges
// in flight per wave. Packed fp16 math.
__global__ __launch_bounds__(256) void k_aggregate(
    const __half* __restrict__ H, const int* __restrict__ row_off,
    const int2* __restrict__ csr, const float* __restrict__ bias,
    __half* __restrict__ Xout, int n) {
  int node = (int)((blockIdx.x * blockDim.x + threadIdx.x) >> 6);
  if (node >= n) return;
  int lane = threadIdx.x & 63;
  int q = lane >> 4, l4 = lane & 15;
  int beg = row_off[node], end = row_off[node + 1];
  const unsigned NEG = 0xFC00FC00u;  // packed half2(-inf,-inf)
  h2 m0 = *(const h2*)&NEG, m1 = m0, m2 = m0, m3 = m0;
  int j = beg + q;
  for (; j + 12 < end; j += 16) {
    int2 e0 = csr[j];
    int2 e1 = csr[j + 4];
    int2 e2 = csr[j + 8];
    int2 e3 = csr[j + 12];
    _Float16 w0 = (_Float16)__int_as_float(e0.y);
    _Float16 w1 = (_Float16)__int_as_float(e1.y);
    _Float16 w2 = (_Float16)__int_as_float(e2.y);
    _Float16 w3 = (_Float16)__int_as_float(e3.y);
    uint4 r0 = *(const uint4*)(H + ((size_t)e0.x << 7) + (l4 << 3));
    uint4 r1 = *(const uint4*)(H + ((size_t)e1.x << 7) + (l4 << 3));
    uint4 r2 = *(const uint4*)(H + ((size_t)e2.x << 7) + (l4 << 3));
    uint4 r3 = *(const uint4*)(H + ((size_t)e3.x << 7) + (l4 << 3));
    m0 = pk_max(m0, *(h2*)&r0.x * w0);
    m1 = pk_max(m1, *(h2*)&r0.y * w0);
    m2 = pk_max(m2, *(h2*)&r0.z * w0);
    m3 = pk_max(m3, *(h2*)&r0.w * w0);
    m0 = pk_max(m0, *(h2*)&r1.x * w1);
    m1 = pk_max(m1, *(h2*)&r1.y * w1);
    m2 = pk_max(m2, *(h2*)&r1.z * w1);
    m3 = pk_max(m3, *(h2*)&r1.w * w1);
    m0 = pk_max(m0, *(h2*)&r2.x * w2);
    m1 = pk_max(m1, *(h2*)&r2.y * w2);
    m2 = pk_max(m2, *(h2*)&r2.z * w2);
    m3 = pk_max(m3, *(h2*)&r2.w * w2);
    m0 = pk_max(m0, *(h2*)&r3.x * w3);
    m1 = pk_max(m1, *(h2*)&r3.y * w3);
    m2 = pk_max(m2, *(h2*)&r3.z * w3);
    m3 = pk_max(m3, *(h2*)&r3.w * w3);
  }
  for (; j < end; j += 4) {
    int2 e0 = csr[j];
    _Float16 w0 = (_Float16)__int_as_float(e0.y);
    uint4 r0 = *(const uint4*)(H + ((size_t)e0.x << 7) + (l4 << 3));
    m0 = pk_max(m0, *(h2*)&r0.x * w0);
    m1 = pk_max(m1, *(h2*)&r0.y * w0);
    m2 = pk_max(m2, *(h2*)&r0.z * w0);
    m3 = pk_max(m3, *(h2*)&r0.w * w0);
  }
  #pragma unroll
  for (int d = 16; d <= 32; d <<= 1) {
    unsigned u0 = __shfl_xor(*(unsigned*)&m0, d, 64);
    unsigned u1 = __shfl_xor(*(unsigned*)&m1, d, 64);
    unsigned u2 = __shfl_xor(*(unsigned*)&m2, d, 64);
    unsigned u3 = __shfl_xor(*(unsigned*)&m3, d, 64);
    m0 = pk_max(m0, *(h2*)&u0);
    m1 = pk_max(m1, *(h2*)&u1);
    m2 = pk_max(m2, *(h2*)&u2);
    m3 = pk_max(m3, *(h2*)&u3);
  }
  if (q == 0) {
    float f0x = (float)m0.x, f0y = (float)m0.y;
    float f1x = (float)m1.x, f1y = (float)m1.y;
    float f2x = (float)m2.x, f2y = (float)m2.y;
    float f3x = (float)m3.x, f3y = (float)m3.y;
    if (end == beg) {  // dead (self-loops guarantee deg>=1)
      f0x=f0y=f1x=f1y=f2x=f2y=f3x=f3y = 0.f;
    }
    float4 b0 = ((const float4*)bias)[l4 << 1];
    float4 b1 = ((const float4*)bias)[(l4 << 1) + 1];
    __half2 o0 = __floats2half2_rn(fmaxf(f0x + b0.x, 0.f), fmaxf(f0y + b0.y, 0.f));
    __half2 o1 = __floats2half2_rn(fmaxf(f1x + b0.z, 0.f), fmaxf(f1y + b0.w, 0.f));
    __half2 o2 = __floats2half2_rn(fmaxf(f2x + b1.x, 0.f), fmaxf(f2y + b1.y, 0.f));
    __half2 o3 = __floats2half2_rn(fmaxf(f3x + b1.z, 0.f), fmaxf(f3y + b1.w, 0.f));
    uint4 ov = make_uint4(*(unsigned*)&o0, *(unsigned*)&o1,
                          *(unsigned*)&o2, *(unsigned*)&o3);
    *(uint4*)(Xout + ((size_t)node << 7) + (l4 << 3)) = ov;
  }
}

// ---------------------------------------------------------------- classifier + log_softmax
__global__ __launch_bounds__(256) void k_classifier(
    const __half* __restrict__ X, const float* __restrict__ Wc,
    const float* __restrict__ bc, float* __restrict__ out, int n) {
  __shared__ float sW[HID * NCLS];
  __shared__ float sx[8][HID];
  int tid = threadIdx.x;
  #pragma unroll
  for (int i = 0; i < 4; ++i)
    ((float4*)sW)[tid + 256 * i] = ((const float4*)Wc)[tid + 256 * i];
  int node0 = blockIdx.x * 8;
  {
    int r = tid >> 5, c = (tid & 31) << 2;
    if (node0 + r < n) {
      __half2 p0 = *(const __half2*)&X[(size_t)(node0 + r) * HID + c];
      __half2 p1 = *(const __half2*)&X[(size_t)(node0 + r) * HID + c + 2];
      float2 f0 = __half22float2(p0), f1 = __half22float2(p1);
      sx[r][c] = f0.x; sx[r][c + 1] = f0.y; sx[r][c + 2] = f1.x; sx[r][c + 3] = f1.y;
    }
  }
  __syncthreads();
  int g = tid >> 5, c = tid & 31;
  int node = node0 + g;
  if (node >= n) return;
  float acc = bc[c];
  #pragma unroll 8
  for (int k = 0; k < HID; ++k)
    acc = fmaf(sx[g][k], sW[k * NCLS + c], acc);
  float m = acc;
  #pragma unroll
  for (int off = 16; off; off >>= 1) m = fmaxf(m, __shfl_xor(m, off, 32));
  float e = expf(acc - m);
  float s = e;
  #pragma unroll
  for (int off = 16; off; off >>= 1) s += __shfl_xor(s, off, 32);
  out[(size_t)node * NCLS + c] = acc - m - logf(s);
}

// ---------------------------------------------------------------- launch
extern "C" void kernel_launch(void* const* d_in, const int* in_sizes, int n_in,
                              void* d_out, int out_size, void* d_ws, size_t ws_size,
                              hipStream_t stream) {
  const float* x    = (const float*)d_in[0];
  const int*   ei   = (const int*)d_in[1];
  const float* norm = (const float*)d_in[2];
  const float* Ws   = (const float*)d_in[3];
  const float* bs   = (const float*)d_in[4];
  const float* Wc   = (const float*)d_in[5];
  const float* bc   = (const float*)d_in[6];
  float* out = (float*)d_out;

  const int N = in_sizes[0] / HID;
  const int E = in_sizes[1] / 2;
  const int L = in_sizes[3] / (HID * HID);
  const int T = E + N;
  const int NB = (N + 511) >> 9;

  char* p = (char*)d_ws;
  auto alloc = [&](size_t bytes) {
    char* r = p; p += (bytes + 255) & ~(size_t)255; return r;
  };
  __half* xa         = (__half*)alloc((size_t)N * HID * 2);
  __half* xb         = (__half*)alloc((size_t)N * HID * 2);
  __half* hbuf       = (__half*)alloc((size_t)N * HID * 2);
  __half* Wt         = (__half*)alloc((size_t)L * HID * HID * 2);
  int*    row_off    = (int*)alloc(((size_t)N + 1) * 4);
  int*    bucket_cur = (int*)alloc(256 * 4);
  int*    bucket_off = (int*)alloc(257 * 4);
  int2*   bins       = (int2*)alloc((size_t)NB * BCAP * 8);
  int2*   csr        = (int2*)alloc((size_t)T * 8);
  (void)ws_size; (void)n_in; (void)out_size;

  hipMemsetAsync(bucket_cur, 0, 256 * 4, stream);
  k_prep_x<<<(N * 32 + 255) / 256, 256, 0, stream>>>(x, xa, N * 32);
  k_prep_w<<<(L * HID * HID + 255) / 256, 256, 0, stream>>>(Ws, Wt, L * HID * HID);
  k_bin<<<(T + 8191) / 8192, 1024, 0, stream>>>(ei, norm, bucket_cur, bins, E, T);
  k_bscan<<<1, 256, 0, stream>>>(bucket_cur, bucket_off, NB);
  k_sortbucket<<<NB, 1024, 0, stream>>>(bins, bucket_off, csr, row_off, N, NB);

  __half* xin = xa;
  __half* xout = xb;
  for (int l = 0; l < L; ++l) {
    k_gemm_mfma<<<(N + 127) / 128, 256, 0, stream>>>(
        xin, Wt + (size_t)l * HID * HID, hbuf, N);
    k_aggregate<<<(N + 3) / 4, 256, 0, stream>>>(
        hbuf, row_off, csr, bs + (size_t)l * HID, xout, N);
    __half* tmp = xin; xin = xout; xout = tmp;
  }
  k_classifier<<<(N + 7) / 8, 256, 0, stream>>>(xin, Wc, bc, out, N);
}